// Round 7
// baseline (262.176 us; speedup 1.0000x reference)
//
#include <hip/hip_runtime.h>

typedef unsigned int uint;
typedef unsigned short ushort;

using bf16x8 = __attribute__((ext_vector_type(8))) short;
using f32x4  = __attribute__((ext_vector_type(4))) float;

// ---- bf16 helpers (bf16 = upper 16 bits of fp32) ----
__device__ __forceinline__ float b2f(ushort u) {
  union { uint i; float f; } v; v.i = ((uint)u) << 16; return v.f;
}
// round-to-nearest-even fp32 -> bf16
__device__ __forceinline__ ushort f2b(float f) {
  union { float f; uint i; } v; v.f = f;
  uint r = (v.i + 0x7fffu + ((v.i >> 16) & 1u)) >> 16;
  return (ushort)r;
}
__device__ __forceinline__ bf16x8 ldfrag(const ushort* p) {
  union { uint4 u; bf16x8 v; } x; x.u = *(const uint4*)p; return x.v;
}
// pack 8 fp32 (two float4) -> bf16x8 fragment
__device__ __forceinline__ bf16x8 pack8(const float4 a, const float4 b) {
  union { uint4 u; bf16x8 v; } x;
  x.u.x = (uint)f2b(a.x) | ((uint)f2b(a.y) << 16);
  x.u.y = (uint)f2b(a.z) | ((uint)f2b(a.w) << 16);
  x.u.z = (uint)f2b(b.x) | ((uint)f2b(b.y) << 16);
  x.u.w = (uint)f2b(b.z) | ((uint)f2b(b.w) << 16);
  return x.v;
}

// =====================================================================
// Kernel 1 (R7): 3 THREADS PER SAMPLE — occupancy fix.
// R0-R6 post-mortems: compiler pins VGPR=84 and re-loads x per use
// cluster regardless of asm/volatile tricks; at 2 waves/SIMD (1
// thread/sample, grid-capped) the reload latency cannot be hidden ->
// VALUBusy 25-50%, conv 52-113 µs while VALU busy-time is only ~27 µs.
// Fix occupancy instead of regalloc: thread q in {0,1,2} computes only
// the h1 row band needed by conv2 output row qr=q ({0-2},{1-4},{3-5};
// +67% conv1 dup) then its 18 h2 outputs. 393216 threads = 6
// waves/SIMD (3x). q is per-WAVE (wave-uniform branches, no lane
// divergence). h2 merged via 16.9 KB LDS stage, stored coalesced.
// =====================================================================
template <int Q>
__device__ __forceinline__ void conv_sample(
    const float* __restrict__ xs,
    const float* __restrict__ w1g, const float* __restrict__ b1g,
    const float* __restrict__ w2g, const float* __restrict__ b2g,
    ushort* __restrict__ strow) {
  constexpr int HRLO = (Q == 0) ? 0 : (Q == 1) ? 1 : 3;
  constexpr int HRHI = (Q == 0) ? 2 : (Q == 1) ? 4 : 5;   // inclusive
  constexpr int NR = HRHI - HRLO + 1;
  constexpr int F4LO = (Q == 0) ? 0 : (Q == 1) ? 3 : 15;
  constexpr int F4HI = (Q == 0) ? 20 : 31;                // inclusive

  // x elems needed: rows 2*HRLO-1 .. 2*HRHI+2 (clamped, <128)
  float xv[128];
#pragma unroll
  for (int i = F4LO; i <= F4HI; ++i) {
    const float4 v = ((const float4*)xs)[i];
    xv[4 * i + 0] = v.x; xv[4 * i + 1] = v.y;
    xv[4 * i + 2] = v.z; xv[4 * i + 3] = v.w;
  }

  float w1[3][9], b1[3];
#pragma unroll
  for (int c = 0; c < 3; ++c) {
    b1[c] = b1g[c];
#pragma unroll
    for (int q = 0; q < 9; ++q) w1[c][q] = w1g[c * 9 + q];
  }

  // conv1+pool+relu for needed h1 rows only
  float h1[3][NR][6];
#pragma unroll
  for (int ri = 0; ri < NR; ++ri) {
    const int hr = HRLO + ri;                 // constexpr per unroll iter
#pragma unroll
    for (int pc = 0; pc < 6; ++pc)
#pragma unroll
      for (int ch = 0; ch < 3; ++ch) {
        float m = -3.0e38f;
#pragma unroll
        for (int dr = 0; dr < 2; ++dr)
#pragma unroll
          for (int dc = 0; dc < 2; ++dc) {
            float a = 0.f;
#pragma unroll
            for (int ky = 0; ky < 3; ++ky)
#pragma unroll
              for (int kx = 0; kx < 3; ++kx) {
                const int r = 2 * hr + dr + ky - 1;
                const int c = 2 * pc + dc + kx - 1;
                if (r >= 0 && r < 12 && c >= 0 && c < 12 && (12 * r + c) < 128)
                  a = fmaf(w1[ch][ky * 3 + kx], xv[12 * r + c], a);  // folds
              }
            m = fmaxf(m, a);
          }
        h1[ch][ri][pc] = fmaxf(m + b1[ch], 0.f);
      }
  }

  // conv2+pool+relu for output row qr=Q, all 6 channels, qc 0..2
#pragma unroll
  for (int o = 0; o < 6; ++o) {
    float w2[27];
#pragma unroll
    for (int q = 0; q < 27; ++q) w2[q] = w2g[o * 27 + q];
    const float bo = b2g[o];
#pragma unroll
    for (int qc = 0; qc < 3; ++qc) {
      float m = -3.0e38f;
#pragma unroll
      for (int dr = 0; dr < 2; ++dr)
#pragma unroll
        for (int dc = 0; dc < 2; ++dc) {
          float a = 0.f;
#pragma unroll
          for (int i = 0; i < 3; ++i)
#pragma unroll
            for (int ky = 0; ky < 3; ++ky)
#pragma unroll
              for (int kx = 0; kx < 3; ++kx) {
                const int yy = 2 * Q + dr + ky - 1;
                const int xx = 2 * qc + dc + kx - 1;
                if (yy >= HRLO && yy <= HRHI && xx >= 0 && xx < 6)  // folds
                  a = fmaf(w2[i * 9 + ky * 3 + kx], h1[i][yy - HRLO][xx], a);
              }
          m = fmaxf(m, a);
        }
      strow[o * 9 + Q * 3 + qc] = f2b(fmaxf(m + bo, 0.f));
    }
  }
  // one thread per sample zero-fills k=54..63 (byte offset 108, 4-aligned)
  if (Q == 2) {
    uint* p = (uint*)(strow + 54);
#pragma unroll
    for (int q = 0; q < 5; ++q) p[q] = 0u;
  }
}

__global__ __launch_bounds__(384, 6) void conv_kernel_r7(
    const float* __restrict__ x,
    const float* __restrict__ w1g, const float* __restrict__ b1g,
    const float* __restrict__ w2g, const float* __restrict__ b2g,
    ushort* __restrict__ h2ws) {
  // stage: 128 samples x 66 ushorts (132B rows: bank stride 33 -> +1
  // bank/lane, conflict-free u16 writes and u32 reads)
  __shared__ ushort h2st[128][66];   // 16896 B

  const int t = threadIdx.x;
  const int s0 = blockIdx.x * 128;
  const int wv = t >> 6;                  // 0..5
  const int q  = (wv < 3) ? wv : wv - 3;  // wave-uniform
  const int sg = (wv < 3) ? 0 : 1;
  const int si = sg * 64 + (t & 63);      // sample-local 0..127

  const float* xs = x + (size_t)(s0 + si) * 128;
  ushort* strow = &h2st[si][0];

  if (q == 0)      conv_sample<0>(xs, w1g, b1g, w2g, b2g, strow);
  else if (q == 1) conv_sample<1>(xs, w1g, b1g, w2g, b2g, strow);
  else             conv_sample<2>(xs, w1g, b1g, w2g, b2g, strow);

  __syncthreads();

  // cooperative coalesced store: 128 rows x 32 dwords = 4096 u32...
  // actually 64 shorts = 32 dwords per row -> 4096 u32 total? No:
  // 128 * 32 = 4096 dwords; 384 threads -> 11 iters? Recount: 128
  // samples x 64 ushorts = 8192 ushorts = 4096 u32. 4096/384 = 10.67.
#pragma unroll
  for (int i = 0; i < 11; ++i) {
    const int f = t + 384 * i;            // 0..4223
    if (f < 4096) {
      const int sr = f >> 5, dw = f & 31;
      const uint v = *(const uint*)&h2st[sr][dw * 2];
      ((uint*)h2ws)[((size_t)(s0 + sr) << 5) + dw] = v;
    }
  }
}

// =====================================================================
// Kernel 2 (logic unchanged from R4 "diet", renamed): swapped-D MFMA
// FC, minimal LDS.
//  - phase1 B-frags (h2) loaded DIRECT from ws (fragment layout == ws
//    rows); phase2 A-frags (out_w) loaded DIRECT from global fp32.
//  - LDS only: w1s (18.4KB) + tA exchange (33.8KB) + biases = 52KB
//    -> 3 blocks/CU. 2 barriers.
// =====================================================================
__global__ __launch_bounds__(256, 3) void fc_kernel_r7(
    const ushort* __restrict__ h2ws,
    const float* __restrict__ fc1w, const float* __restrict__ fc1b,
    const float* __restrict__ outw, const float* __restrict__ outb,
    float* __restrict__ out) {
  __shared__ __align__(16) ushort w1s[128][72];   // 18432 B
  __shared__ __align__(16) ushort tA[128][132];   // 33792 B
  __shared__ __align__(16) float fb1[128];
  __shared__ __align__(16) float ob[128];

  const int t = threadIdx.x;
  const int s0 = blockIdx.x * 128;
  const int lane = t & 63, wv = t >> 6;
  const int quad = lane >> 4, lm = lane & 15;

  // ---- prefetch all phase1 B-fragments (h2) direct from ws ----
  bf16x8 bh[2][8];
#pragma unroll
  for (int st = 0; st < 8; ++st) {
    const ushort* rp = h2ws + (size_t)(s0 + 16 * st + lm) * 64 + quad * 8;
    bh[0][st] = ldfrag(rp);
    bh[1][st] = ldfrag(rp + 32);
  }

  if (t < 128) { fb1[t] = fc1b[t]; ob[t] = outb[t]; }

  // stage fc1_w [128][54] fp32 -> bf16 layout w1s[j][k]
#pragma unroll
  for (int i = 0; i < 27; ++i) {
    const int f = t + 256 * i;            // 0..6911
    const int n = f / 54, k = f - 54 * n;
    w1s[n][k] = f2b(fc1w[f]);
  }
  // zero-pad w1s k=54..63 (byte offset 108, dword aligned)
  if (t < 128) {
    uint* p = (uint*)&w1s[t][54];
#pragma unroll
    for (int q = 0; q < 5; ++q) p[q] = 0u;
  }
  __syncthreads();   // barrier #1: w1s ready

  // ---- phase1 MFMA (swapped): acc[mt][st] = w1[32wv+16mt+lm] x h2-frag
  f32x4 acc[2][8];
#pragma unroll
  for (int mt = 0; mt < 2; ++mt)
#pragma unroll
    for (int st = 0; st < 8; ++st) acc[mt][st] = (f32x4){0.f, 0.f, 0.f, 0.f};

#pragma unroll
  for (int kk = 0; kk < 2; ++kk) {
    const int ko = kk * 32 + quad * 8;
    bf16x8 aw[2];
#pragma unroll
    for (int mt = 0; mt < 2; ++mt)
      aw[mt] = ldfrag(&w1s[32 * wv + 16 * mt + lm][ko]);
#pragma unroll
    for (int mt = 0; mt < 2; ++mt)
#pragma unroll
      for (int st = 0; st < 8; ++st)
        acc[mt][st] = __builtin_amdgcn_mfma_f32_16x16x32_bf16(
            aw[mt], bh[kk][st], acc[mt][st], 0, 0, 0);
  }

  // t = relu(acc + b) -> bf16 -> tA[s][j]; lane holds 4 consecutive j
  // at fixed s -> one 8B write per (mt,st).
#pragma unroll
  for (int mt = 0; mt < 2; ++mt) {
    const int jb = 32 * wv + 16 * mt + quad * 4;
    const float4 bj = *(const float4*)&fb1[jb];
#pragma unroll
    for (int st = 0; st < 8; ++st) {
      const int sR = 16 * st + lm;
      const float v0 = fmaxf(acc[mt][st][0] + bj.x, 0.f);
      const float v1 = fmaxf(acc[mt][st][1] + bj.y, 0.f);
      const float v2 = fmaxf(acc[mt][st][2] + bj.z, 0.f);
      const float v3 = fmaxf(acc[mt][st][3] + bj.w, 0.f);
      uint2 pv;
      pv.x = (uint)f2b(v0) | ((uint)f2b(v1) << 16);
      pv.y = (uint)f2b(v2) | ((uint)f2b(v3) << 16);
      *(uint2*)&tA[sR][jb] = pv;
    }
  }
  __syncthreads();   // barrier #2: tA ready

  // ---- phase2 MFMA (swapped): A-frags direct from out_w fp32
  f32x4 acc2[2][8];
#pragma unroll
  for (int mt = 0; mt < 2; ++mt)
#pragma unroll
    for (int st = 0; st < 8; ++st) acc2[mt][st] = (f32x4){0.f, 0.f, 0.f, 0.f};

#pragma unroll
  for (int kk = 0; kk < 4; ++kk) {
    const int ko = kk * 32 + quad * 8;
    bf16x8 ao[2], bt[8];
#pragma unroll
    for (int mt = 0; mt < 2; ++mt) {
      const float* rp = outw + (size_t)(32 * wv + 16 * mt + lm) * 128 + ko;
      const float4 v0 = *(const float4*)rp;
      const float4 v1 = *(const float4*)(rp + 4);
      ao[mt] = pack8(v0, v1);
    }
#pragma unroll
    for (int st = 0; st < 8; ++st)
      bt[st] = ldfrag(&tA[16 * st + lm][ko]);
#pragma unroll
    for (int mt = 0; mt < 2; ++mt)
#pragma unroll
      for (int st = 0; st < 8; ++st)
        acc2[mt][st] = __builtin_amdgcn_mfma_f32_16x16x32_bf16(
            ao[mt], bt[st], acc2[mt][st], 0, 0, 0);
  }

  // epilogue: lane holds 4 consecutive o at fixed s -> dwordx4 stores
#pragma unroll
  for (int mt = 0; mt < 2; ++mt) {
    const int obase = 32 * wv + 16 * mt + quad * 4;
    const float4 b4 = *(const float4*)&ob[obase];
#pragma unroll
    for (int st = 0; st < 8; ++st) {
      const int srow = s0 + 16 * st + lm;
      float4 o4;
      o4.x = acc2[mt][st][0] + b4.x;
      o4.y = acc2[mt][st][1] + b4.y;
      o4.z = acc2[mt][st][2] + b4.z;
      o4.w = acc2[mt][st][3] + b4.w;
      *(float4*)&out[(size_t)srow * 128 + obase] = o4;
    }
  }
}

extern "C" void kernel_launch(void* const* d_in, const int* in_sizes, int n_in,
                              void* d_out, int out_size, void* d_ws, size_t ws_size,
                              hipStream_t stream) {
  const float* x    = (const float*)d_in[0];
  const float* w1   = (const float*)d_in[1];
  const float* b1   = (const float*)d_in[2];
  const float* w2   = (const float*)d_in[3];
  const float* b2   = (const float*)d_in[4];
  const float* fc1w = (const float*)d_in[5];
  const float* fc1b = (const float*)d_in[6];
  const float* outw = (const float*)d_in[7];
  const float* outb = (const float*)d_in[8];
  float* outp = (float*)d_out;
  ushort* ws  = (ushort*)d_ws;   // h2 staging: N x 64 bf16 = 16.8 MB

  const int N = in_sizes[0] / 128;   // 131072

  conv_kernel_r7<<<N / 128, 384, 0, stream>>>(x, w1, b1, w2, b2, ws);
  fc_kernel_r7<<<N / 128, 256, 0, stream>>>(ws, fc1w, fc1b, outw, outb, outp);
}

// Round 8
// 205.616 us; speedup vs baseline: 1.2751x; 1.2751x over previous
//
#include <hip/hip_runtime.h>

typedef unsigned int uint;
typedef unsigned short ushort;

using bf16x8 = __attribute__((ext_vector_type(8))) short;
using f32x4  = __attribute__((ext_vector_type(4))) float;

// ---- bf16 helpers (bf16 = upper 16 bits of fp32) ----
__device__ __forceinline__ float b2f(ushort u) {
  union { uint i; float f; } v; v.i = ((uint)u) << 16; return v.f;
}
// round-to-nearest-even fp32 -> bf16
__device__ __forceinline__ ushort f2b(float f) {
  union { float f; uint i; } v; v.f = f;
  uint r = (v.i + 0x7fffu + ((v.i >> 16) & 1u)) >> 16;
  return (ushort)r;
}
__device__ __forceinline__ bf16x8 ldfrag(const ushort* p) {
  union { uint4 u; bf16x8 v; } x; x.u = *(const uint4*)p; return x.v;
}
// pack 8 fp32 (two float4) -> bf16x8 fragment
__device__ __forceinline__ bf16x8 pack8(const float4 a, const float4 b) {
  union { uint4 u; bf16x8 v; } x;
  x.u.x = (uint)f2b(a.x) | ((uint)f2b(a.y) << 16);
  x.u.y = (uint)f2b(a.z) | ((uint)f2b(a.w) << 16);
  x.u.z = (uint)f2b(b.x) | ((uint)f2b(b.y) << 16);
  x.u.w = (uint)f2b(b.z) | ((uint)f2b(b.w) << 16);
  return x.v;
}

// =====================================================================
// Kernel 1 (R8): 3 threads/sample split — R7 structure, SPILL FIXED.
// R7's __launch_bounds__(384,6) forced a ~85-VGPR budget -> allocator
// spilled xv/h1 to scratch (VGPR=40, WRITE_SIZE 80MB = 16.4 output +
// 64MB scratch, conv 144 µs). Split itself is correctness-verified.
// Fix: (384,4) -> 128-VGPR budget; live set (~50-80) fits, no spill.
// Grid provides 6 waves/SIMD (1024 blocks x 384 thr, 4 blocks/CU, LDS
// 16.9KB x 4 = 68KB); occupancy = min(6, 512/VGPR_actual) >= 4.
// Thread q in {0,1,2} computes the h1 row band for conv2 output row
// qr=q ({0-2},{1-4},{3-5}; +67% conv1 dup), then its 18 h2 outputs.
// q is per-WAVE (wave-uniform branches). h2 merged in LDS, stored
// coalesced as u32.
// =====================================================================
template <int Q>
__device__ __forceinline__ void conv_sample(
    const float* __restrict__ xs,
    const float* __restrict__ w1g, const float* __restrict__ b1g,
    const float* __restrict__ w2g, const float* __restrict__ b2g,
    ushort* __restrict__ strow) {
  constexpr int HRLO = (Q == 0) ? 0 : (Q == 1) ? 1 : 3;
  constexpr int HRHI = (Q == 0) ? 2 : (Q == 1) ? 4 : 5;   // inclusive
  constexpr int NR = HRHI - HRLO + 1;
  constexpr int F4LO = (Q == 0) ? 0 : (Q == 1) ? 3 : 15;
  constexpr int F4HI = (Q == 0) ? 20 : 31;                // inclusive

  // x elems needed: rows 2*HRLO-1 .. 2*HRHI+2 (clamped, <128)
  float xv[128];
#pragma unroll
  for (int i = F4LO; i <= F4HI; ++i) {
    const float4 v = ((const float4*)xs)[i];
    xv[4 * i + 0] = v.x; xv[4 * i + 1] = v.y;
    xv[4 * i + 2] = v.z; xv[4 * i + 3] = v.w;
  }

  float w1[3][9], b1[3];
#pragma unroll
  for (int c = 0; c < 3; ++c) {
    b1[c] = b1g[c];
#pragma unroll
    for (int q = 0; q < 9; ++q) w1[c][q] = w1g[c * 9 + q];
  }

  // conv1+pool+relu for needed h1 rows only
  float h1[3][NR][6];
#pragma unroll
  for (int ri = 0; ri < NR; ++ri) {
    const int hr = HRLO + ri;                 // constexpr per unroll iter
#pragma unroll
    for (int pc = 0; pc < 6; ++pc)
#pragma unroll
      for (int ch = 0; ch < 3; ++ch) {
        float m = -3.0e38f;
#pragma unroll
        for (int dr = 0; dr < 2; ++dr)
#pragma unroll
          for (int dc = 0; dc < 2; ++dc) {
            float a = 0.f;
#pragma unroll
            for (int ky = 0; ky < 3; ++ky)
#pragma unroll
              for (int kx = 0; kx < 3; ++kx) {
                const int r = 2 * hr + dr + ky - 1;
                const int c = 2 * pc + dc + kx - 1;
                if (r >= 0 && r < 12 && c >= 0 && c < 12 && (12 * r + c) < 128)
                  a = fmaf(w1[ch][ky * 3 + kx], xv[12 * r + c], a);  // folds
              }
            m = fmaxf(m, a);
          }
        h1[ch][ri][pc] = fmaxf(m + b1[ch], 0.f);
      }
  }

  // conv2+pool+relu for output row qr=Q, all 6 channels, qc 0..2
#pragma unroll
  for (int o = 0; o < 6; ++o) {
    float w2[27];
#pragma unroll
    for (int q = 0; q < 27; ++q) w2[q] = w2g[o * 27 + q];
    const float bo = b2g[o];
#pragma unroll
    for (int qc = 0; qc < 3; ++qc) {
      float m = -3.0e38f;
#pragma unroll
      for (int dr = 0; dr < 2; ++dr)
#pragma unroll
        for (int dc = 0; dc < 2; ++dc) {
          float a = 0.f;
#pragma unroll
          for (int i = 0; i < 3; ++i)
#pragma unroll
            for (int ky = 0; ky < 3; ++ky)
#pragma unroll
              for (int kx = 0; kx < 3; ++kx) {
                const int yy = 2 * Q + dr + ky - 1;
                const int xx = 2 * qc + dc + kx - 1;
                if (yy >= HRLO && yy <= HRHI && xx >= 0 && xx < 6)  // folds
                  a = fmaf(w2[i * 9 + ky * 3 + kx], h1[i][yy - HRLO][xx], a);
              }
          m = fmaxf(m, a);
        }
      strow[o * 9 + Q * 3 + qc] = f2b(fmaxf(m + bo, 0.f));
    }
  }
  // one thread per sample zero-fills k=54..63 (byte offset 108, 4-aligned)
  if (Q == 2) {
    uint* p = (uint*)(strow + 54);
#pragma unroll
    for (int q = 0; q < 5; ++q) p[q] = 0u;
  }
}

__global__ __launch_bounds__(384, 4) void conv_kernel_r8(
    const float* __restrict__ x,
    const float* __restrict__ w1g, const float* __restrict__ b1g,
    const float* __restrict__ w2g, const float* __restrict__ b2g,
    ushort* __restrict__ h2ws) {
  // stage: 128 samples x 66 ushorts (132B rows: bank stride 33 ->
  // conflict-free u16 writes and u32 reads)
  __shared__ ushort h2st[128][66];   // 16896 B

  const int t = threadIdx.x;
  const int s0 = blockIdx.x * 128;
  const int wv = t >> 6;                  // 0..5
  const int q  = (wv < 3) ? wv : wv - 3;  // wave-uniform
  const int sg = (wv < 3) ? 0 : 1;
  const int si = sg * 64 + (t & 63);      // sample-local 0..127

  const float* xs = x + (size_t)(s0 + si) * 128;
  ushort* strow = &h2st[si][0];

  if (q == 0)      conv_sample<0>(xs, w1g, b1g, w2g, b2g, strow);
  else if (q == 1) conv_sample<1>(xs, w1g, b1g, w2g, b2g, strow);
  else             conv_sample<2>(xs, w1g, b1g, w2g, b2g, strow);

  __syncthreads();

  // cooperative coalesced store: 128 samples x 64 ushorts = 4096 u32
#pragma unroll
  for (int i = 0; i < 11; ++i) {
    const int f = t + 384 * i;            // 0..4223
    if (f < 4096) {
      const int sr = f >> 5, dw = f & 31;
      const uint v = *(const uint*)&h2st[sr][dw * 2];
      ((uint*)h2ws)[((size_t)(s0 + sr) << 5) + dw] = v;
    }
  }
}

// =====================================================================
// Kernel 2 (logic unchanged from R4 "diet", renamed): swapped-D MFMA
// FC, minimal LDS.
//  - phase1 B-frags (h2) loaded DIRECT from ws (fragment layout == ws
//    rows); phase2 A-frags (out_w) loaded DIRECT from global fp32.
//  - LDS only: w1s (18.4KB) + tA exchange (33.8KB) + biases = 52KB
//    -> 3 blocks/CU. 2 barriers.
// =====================================================================
__global__ __launch_bounds__(256, 3) void fc_kernel_r8(
    const ushort* __restrict__ h2ws,
    const float* __restrict__ fc1w, const float* __restrict__ fc1b,
    const float* __restrict__ outw, const float* __restrict__ outb,
    float* __restrict__ out) {
  __shared__ __align__(16) ushort w1s[128][72];   // 18432 B
  __shared__ __align__(16) ushort tA[128][132];   // 33792 B
  __shared__ __align__(16) float fb1[128];
  __shared__ __align__(16) float ob[128];

  const int t = threadIdx.x;
  const int s0 = blockIdx.x * 128;
  const int lane = t & 63, wv = t >> 6;
  const int quad = lane >> 4, lm = lane & 15;

  // ---- prefetch all phase1 B-fragments (h2) direct from ws ----
  bf16x8 bh[2][8];
#pragma unroll
  for (int st = 0; st < 8; ++st) {
    const ushort* rp = h2ws + (size_t)(s0 + 16 * st + lm) * 64 + quad * 8;
    bh[0][st] = ldfrag(rp);
    bh[1][st] = ldfrag(rp + 32);
  }

  if (t < 128) { fb1[t] = fc1b[t]; ob[t] = outb[t]; }

  // stage fc1_w [128][54] fp32 -> bf16 layout w1s[j][k]
#pragma unroll
  for (int i = 0; i < 27; ++i) {
    const int f = t + 256 * i;            // 0..6911
    const int n = f / 54, k = f - 54 * n;
    w1s[n][k] = f2b(fc1w[f]);
  }
  // zero-pad w1s k=54..63 (byte offset 108, dword aligned)
  if (t < 128) {
    uint* p = (uint*)&w1s[t][54];
#pragma unroll
    for (int q = 0; q < 5; ++q) p[q] = 0u;
  }
  __syncthreads();   // barrier #1: w1s ready

  // ---- phase1 MFMA (swapped): acc[mt][st] = w1[32wv+16mt+lm] x h2-frag
  f32x4 acc[2][8];
#pragma unroll
  for (int mt = 0; mt < 2; ++mt)
#pragma unroll
    for (int st = 0; st < 8; ++st) acc[mt][st] = (f32x4){0.f, 0.f, 0.f, 0.f};

#pragma unroll
  for (int kk = 0; kk < 2; ++kk) {
    const int ko = kk * 32 + quad * 8;
    bf16x8 aw[2];
#pragma unroll
    for (int mt = 0; mt < 2; ++mt)
      aw[mt] = ldfrag(&w1s[32 * wv + 16 * mt + lm][ko]);
#pragma unroll
    for (int mt = 0; mt < 2; ++mt)
#pragma unroll
      for (int st = 0; st < 8; ++st)
        acc[mt][st] = __builtin_amdgcn_mfma_f32_16x16x32_bf16(
            aw[mt], bh[kk][st], acc[mt][st], 0, 0, 0);
  }

  // t = relu(acc + b) -> bf16 -> tA[s][j]; lane holds 4 consecutive j
  // at fixed s -> one 8B write per (mt,st).
#pragma unroll
  for (int mt = 0; mt < 2; ++mt) {
    const int jb = 32 * wv + 16 * mt + quad * 4;
    const float4 bj = *(const float4*)&fb1[jb];
#pragma unroll
    for (int st = 0; st < 8; ++st) {
      const int sR = 16 * st + lm;
      const float v0 = fmaxf(acc[mt][st][0] + bj.x, 0.f);
      const float v1 = fmaxf(acc[mt][st][1] + bj.y, 0.f);
      const float v2 = fmaxf(acc[mt][st][2] + bj.z, 0.f);
      const float v3 = fmaxf(acc[mt][st][3] + bj.w, 0.f);
      uint2 pv;
      pv.x = (uint)f2b(v0) | ((uint)f2b(v1) << 16);
      pv.y = (uint)f2b(v2) | ((uint)f2b(v3) << 16);
      *(uint2*)&tA[sR][jb] = pv;
    }
  }
  __syncthreads();   // barrier #2: tA ready

  // ---- phase2 MFMA (swapped): A-frags direct from out_w fp32
  f32x4 acc2[2][8];
#pragma unroll
  for (int mt = 0; mt < 2; ++mt)
#pragma unroll
    for (int st = 0; st < 8; ++st) acc2[mt][st] = (f32x4){0.f, 0.f, 0.f, 0.f};

#pragma unroll
  for (int kk = 0; kk < 4; ++kk) {
    const int ko = kk * 32 + quad * 8;
    bf16x8 ao[2], bt[8];
#pragma unroll
    for (int mt = 0; mt < 2; ++mt) {
      const float* rp = outw + (size_t)(32 * wv + 16 * mt + lm) * 128 + ko;
      const float4 v0 = *(const float4*)rp;
      const float4 v1 = *(const float4*)(rp + 4);
      ao[mt] = pack8(v0, v1);
    }
#pragma unroll
    for (int st = 0; st < 8; ++st)
      bt[st] = ldfrag(&tA[16 * st + lm][ko]);
#pragma unroll
    for (int mt = 0; mt < 2; ++mt)
#pragma unroll
      for (int st = 0; st < 8; ++st)
        acc2[mt][st] = __builtin_amdgcn_mfma_f32_16x16x32_bf16(
            ao[mt], bt[st], acc2[mt][st], 0, 0, 0);
  }

  // epilogue: lane holds 4 consecutive o at fixed s -> dwordx4 stores
#pragma unroll
  for (int mt = 0; mt < 2; ++mt) {
    const int obase = 32 * wv + 16 * mt + quad * 4;
    const float4 b4 = *(const float4*)&ob[obase];
#pragma unroll
    for (int st = 0; st < 8; ++st) {
      const int srow = s0 + 16 * st + lm;
      float4 o4;
      o4.x = acc2[mt][st][0] + b4.x;
      o4.y = acc2[mt][st][1] + b4.y;
      o4.z = acc2[mt][st][2] + b4.z;
      o4.w = acc2[mt][st][3] + b4.w;
      *(float4*)&out[(size_t)srow * 128 + obase] = o4;
    }
  }
}

extern "C" void kernel_launch(void* const* d_in, const int* in_sizes, int n_in,
                              void* d_out, int out_size, void* d_ws, size_t ws_size,
                              hipStream_t stream) {
  const float* x    = (const float*)d_in[0];
  const float* w1   = (const float*)d_in[1];
  const float* b1   = (const float*)d_in[2];
  const float* w2   = (const float*)d_in[3];
  const float* b2   = (const float*)d_in[4];
  const float* fc1w = (const float*)d_in[5];
  const float* fc1b = (const float*)d_in[6];
  const float* outw = (const float*)d_in[7];
  const float* outb = (const float*)d_in[8];
  float* outp = (float*)d_out;
  ushort* ws  = (ushort*)d_ws;   // h2 staging: N x 64 bf16 = 16.8 MB

  const int N = in_sizes[0] / 128;   // 131072

  conv_kernel_r8<<<N / 128, 384, 0, stream>>>(x, w1, b1, w2, b2, ws);
  fc_kernel_r8<<<N / 128, 256, 0, stream>>>(ws, fc1w, fc1b, outw, outb, outp);
}

// Round 9
// 196.818 us; speedup vs baseline: 1.3321x; 1.0447x over previous
//
#include <hip/hip_runtime.h>

typedef unsigned int uint;
typedef unsigned short ushort;

using bf16x8 = __attribute__((ext_vector_type(8))) short;
using f32x4  = __attribute__((ext_vector_type(4))) float;

// ---- bf16 helpers (bf16 = upper 16 bits of fp32) ----
__device__ __forceinline__ float b2f(ushort u) {
  union { uint i; float f; } v; v.i = ((uint)u) << 16; return v.f;
}
// round-to-nearest-even fp32 -> bf16
__device__ __forceinline__ ushort f2b(float f) {
  union { float f; uint i; } v; v.f = f;
  uint r = (v.i + 0x7fffu + ((v.i >> 16) & 1u)) >> 16;
  return (ushort)r;
}
__device__ __forceinline__ bf16x8 ldfrag(const ushort* p) {
  union { uint4 u; bf16x8 v; } x; x.u = *(const uint4*)p; return x.v;
}
// pack 8 fp32 (two float4) -> bf16x8 fragment
__device__ __forceinline__ bf16x8 pack8(const float4 a, const float4 b) {
  union { uint4 u; bf16x8 v; } x;
  x.u.x = (uint)f2b(a.x) | ((uint)f2b(a.y) << 16);
  x.u.y = (uint)f2b(a.z) | ((uint)f2b(a.w) << 16);
  x.u.z = (uint)f2b(b.x) | ((uint)f2b(b.y) << 16);
  x.u.w = (uint)f2b(b.z) | ((uint)f2b(b.w) << 16);
  return x.v;
}

// =====================================================================
// Kernel 1 (R9): COOPERATIVE conv — h1 computed once into LDS.
// Root cause from R0-R8: per-thread state (xv 128 + h1 108) >> VGPR
// budget -> compiler REMATERIALIZES h1 FMA-trees and re-loads x per
// use cluster (VGPR=84/64, no scratch, ~3x VALU amplification:
// 31K executed vs 10.6K nominal wave-inst). Fix: shrink real
// per-thread state so remat has no incentive.
//  conv1: 384 thr = 128 samples x 3 channels; each thread computes
//    h1[ch][6][6] with a 4-row sliding x window (live ~65 regs),
//    writes fp32 h1 to LDS (stride 110 dwords: 2-way bank = free).
//  conv2: 384 thr = 128 samples x 3 channel-pairs; each thread does 2
//    output channels (1944 FMA), reads h1 from LDS per input channel
//    (live ~110 regs incl. w2; grp via readfirstlane -> SGPR weights).
// LDS 73.2 KB -> 2 blocks/CU = 3 waves/SIMD. No remat, no spill.
// =====================================================================
template <int R>
__device__ __forceinline__ void load_row(const float* __restrict__ xs,
                                         float (&d)[12]) {
  if constexpr (R >= 11) {
#pragma unroll
    for (int c = 0; c < 12; ++c) d[c] = 0.f;
  } else if constexpr (R == 10) {
    const float4 a = *(const float4*)(xs + 120);
    const float4 b = *(const float4*)(xs + 124);
    d[0] = a.x; d[1] = a.y; d[2] = a.z; d[3] = a.w;
    d[4] = b.x; d[5] = b.y; d[6] = b.z; d[7] = b.w;
    d[8] = 0.f; d[9] = 0.f; d[10] = 0.f; d[11] = 0.f;
  } else {
#pragma unroll
    for (int q = 0; q < 3; ++q) {
      const float4 v = *(const float4*)(xs + 12 * R + 4 * q);
      d[4 * q + 0] = v.x; d[4 * q + 1] = v.y;
      d[4 * q + 2] = v.z; d[4 * q + 3] = v.w;
    }
  }
}

template <int PR>
__device__ __forceinline__ void conv1_band(const float* __restrict__ xs,
                                           float (&xr)[4][12],
                                           const float (&w1r)[9], float b1v,
                                           float* __restrict__ hlrow) {
  // slide: bring in rows 2PR+1, 2PR+2 (prologue already loaded 0,1,2)
  if constexpr (PR >= 1) {
    load_row<2 * PR + 1>(xs, xr[(2 * PR + 1) & 3]);
    if constexpr (2 * PR + 2 <= 11)
      load_row<2 * PR + 2>(xs, xr[(2 * PR + 2) & 3]);
  }
  float out[6];
#pragma unroll
  for (int pc = 0; pc < 6; ++pc) {
    float m = -3.0e38f;
#pragma unroll
    for (int dr = 0; dr < 2; ++dr)
#pragma unroll
      for (int dc = 0; dc < 2; ++dc) {
        float a = 0.f;
#pragma unroll
        for (int ky = 0; ky < 3; ++ky)
#pragma unroll
          for (int kx = 0; kx < 3; ++kx) {
            const int y = 2 * PR + dr + ky - 1;
            const int cc = 2 * pc + dc + kx - 1;
            if (y >= 0 && y < 12 && cc >= 0 && cc < 12 &&
                (12 * y + cc) < 128)                       // folds
              a = fmaf(w1r[ky * 3 + kx], xr[y & 3][cc], a);
          }
        m = fmaxf(m, a);
      }
    out[pc] = fmaxf(m + b1v, 0.f);
  }
#pragma unroll
  for (int q = 0; q < 3; ++q)
    *(float2*)&hlrow[PR * 6 + 2 * q] = make_float2(out[2 * q], out[2 * q + 1]);
}

__global__ __launch_bounds__(384, 3) void conv_kernel_r9(
    const float* __restrict__ x,
    const float* __restrict__ w1g, const float* __restrict__ b1g,
    const float* __restrict__ w2g, const float* __restrict__ b2g,
    ushort* __restrict__ h2ws) {
  // h1: [si][ch*36 + r*6 + c], row stride 110 dwords (even: float2-able;
  // 110%32=14 -> 2 lanes/bank = free). 56320 B.
  __shared__ float hl[128 * 110];
  __shared__ ushort h2st[128][66];   // 16896 B, stride 33 dwords (odd)

  const int t = threadIdx.x;
  const int s0 = blockIdx.x * 128;
  const int si = t & 127;
  const int grp = __builtin_amdgcn_readfirstlane(t >> 7);  // 0..2, wave-uniform

  const float* xs = x + (size_t)(s0 + si) * 128;

  // ---- conv1: thread computes h1 channel `grp` for sample si ----
  {
    float w1r[9];
#pragma unroll
    for (int q = 0; q < 9; ++q) w1r[q] = w1g[grp * 9 + q];
    const float b1v = b1g[grp];

    float xr[4][12];
    load_row<0>(xs, xr[0]);
    load_row<1>(xs, xr[1]);
    load_row<2>(xs, xr[2]);
    float* hlrow = &hl[si * 110 + grp * 36];

    conv1_band<0>(xs, xr, w1r, b1v, hlrow);
    conv1_band<1>(xs, xr, w1r, b1v, hlrow);
    conv1_band<2>(xs, xr, w1r, b1v, hlrow);
    conv1_band<3>(xs, xr, w1r, b1v, hlrow);
    conv1_band<4>(xs, xr, w1r, b1v, hlrow);
    conv1_band<5>(xs, xr, w1r, b1v, hlrow);
  }
  __syncthreads();   // h1 complete

  // ---- conv2: thread computes out-channels {2grp, 2grp+1} for sample si
  {
    const int o0 = 2 * grp;
    float w2a[27], w2b[27];
#pragma unroll
    for (int q = 0; q < 27; ++q) {
      w2a[q] = w2g[o0 * 27 + q];
      w2b[q] = w2g[(o0 + 1) * 27 + q];
    }
    const float b2a = b2g[o0], b2b = b2g[o0 + 1];
    const float* hbase = &hl[si * 110];

#pragma unroll
    for (int qr = 0; qr < 3; ++qr) {
      const int lo = (qr == 0) ? 0 : 2 * qr - 1;
      const int hi = (qr == 2) ? 5 : 2 * qr + 2;
      float s[2][3][4];
#pragma unroll
      for (int oo = 0; oo < 2; ++oo)
#pragma unroll
        for (int qc = 0; qc < 3; ++qc)
#pragma unroll
          for (int p = 0; p < 4; ++p) s[oo][qc][p] = 0.f;

#pragma unroll
      for (int i = 0; i < 3; ++i) {
        // load this channel's h1 window rows lo..hi (<=4 rows x 6)
        float hwv[4][6];
#pragma unroll
        for (int rr = 0; rr < 4; ++rr) {
          if (lo + rr <= hi) {
#pragma unroll
            for (int q = 0; q < 3; ++q) {
              const float2 p2 =
                  *(const float2*)&hbase[i * 36 + (lo + rr) * 6 + 2 * q];
              hwv[rr][2 * q] = p2.x; hwv[rr][2 * q + 1] = p2.y;
            }
          }
        }
#pragma unroll
        for (int ky = 0; ky < 3; ++ky)
#pragma unroll
          for (int kx = 0; kx < 3; ++kx) {
            const float wa = w2a[i * 9 + ky * 3 + kx];
            const float wb = w2b[i * 9 + ky * 3 + kx];
#pragma unroll
            for (int dr = 0; dr < 2; ++dr) {
              const int y = 2 * qr + dr + ky - 1;
              if (y < lo || y > hi) continue;   // folds (0..5 clamp)
#pragma unroll
              for (int qc = 0; qc < 3; ++qc)
#pragma unroll
                for (int dc = 0; dc < 2; ++dc) {
                  const int xx = 2 * qc + dc + kx - 1;
                  if (xx < 0 || xx > 5) continue;   // folds
                  const float h = hwv[y - lo][xx];
                  s[0][qc][dr * 2 + dc] = fmaf(wa, h, s[0][qc][dr * 2 + dc]);
                  s[1][qc][dr * 2 + dc] = fmaf(wb, h, s[1][qc][dr * 2 + dc]);
                }
            }
          }
      }
      // finalize 6 outputs (2 channels x 3 cols): pool-max + bias + relu
#pragma unroll
      for (int oo = 0; oo < 2; ++oo)
#pragma unroll
        for (int qc = 0; qc < 3; ++qc) {
          const float m = fmaxf(fmaxf(s[oo][qc][0], s[oo][qc][1]),
                                fmaxf(s[oo][qc][2], s[oo][qc][3]));
          const float bv = oo ? b2b : b2a;
          h2st[si][(o0 + oo) * 9 + qr * 3 + qc] = f2b(fmaxf(m + bv, 0.f));
        }
    }
    // zero-pad k=54..63 (byte offset 108, dword aligned)
    if (grp == 2) {
      uint* p = (uint*)&h2st[si][54];
#pragma unroll
      for (int q = 0; q < 5; ++q) p[q] = 0u;
    }
  }
  __syncthreads();   // h2st complete

  // cooperative coalesced store: 128 samples x 64 ushorts = 4096 u32
#pragma unroll
  for (int i = 0; i < 11; ++i) {
    const int f = t + 384 * i;            // 0..4223
    if (f < 4096) {
      const int sr = f >> 5, dw = f & 31;
      const uint v = *(const uint*)&h2st[sr][dw * 2];
      ((uint*)h2ws)[((size_t)(s0 + sr) << 5) + dw] = v;
    }
  }
}

// =====================================================================
// Kernel 2 (logic unchanged from R4 "diet", renamed): swapped-D MFMA
// FC, minimal LDS.
//  - phase1 B-frags (h2) loaded DIRECT from ws (fragment layout == ws
//    rows); phase2 A-frags (out_w) loaded DIRECT from global fp32.
//  - LDS only: w1s (18.4KB) + tA exchange (33.8KB) + biases = 52KB
//    -> 3 blocks/CU. 2 barriers.
// =====================================================================
__global__ __launch_bounds__(256, 3) void fc_kernel_r9(
    const ushort* __restrict__ h2ws,
    const float* __restrict__ fc1w, const float* __restrict__ fc1b,
    const float* __restrict__ outw, const float* __restrict__ outb,
    float* __restrict__ out) {
  __shared__ __align__(16) ushort w1s[128][72];   // 18432 B
  __shared__ __align__(16) ushort tA[128][132];   // 33792 B
  __shared__ __align__(16) float fb1[128];
  __shared__ __align__(16) float ob[128];

  const int t = threadIdx.x;
  const int s0 = blockIdx.x * 128;
  const int lane = t & 63, wv = t >> 6;
  const int quad = lane >> 4, lm = lane & 15;

  // ---- prefetch all phase1 B-fragments (h2) direct from ws ----
  bf16x8 bh[2][8];
#pragma unroll
  for (int st = 0; st < 8; ++st) {
    const ushort* rp = h2ws + (size_t)(s0 + 16 * st + lm) * 64 + quad * 8;
    bh[0][st] = ldfrag(rp);
    bh[1][st] = ldfrag(rp + 32);
  }

  if (t < 128) { fb1[t] = fc1b[t]; ob[t] = outb[t]; }

  // stage fc1_w [128][54] fp32 -> bf16 layout w1s[j][k]
#pragma unroll
  for (int i = 0; i < 27; ++i) {
    const int f = t + 256 * i;            // 0..6911
    const int n = f / 54, k = f - 54 * n;
    w1s[n][k] = f2b(fc1w[f]);
  }
  // zero-pad w1s k=54..63 (byte offset 108, dword aligned)
  if (t < 128) {
    uint* p = (uint*)&w1s[t][54];
#pragma unroll
    for (int q = 0; q < 5; ++q) p[q] = 0u;
  }
  __syncthreads();   // barrier #1: w1s ready

  // ---- phase1 MFMA (swapped): acc[mt][st] = w1[32wv+16mt+lm] x h2-frag
  f32x4 acc[2][8];
#pragma unroll
  for (int mt = 0; mt < 2; ++mt)
#pragma unroll
    for (int st = 0; st < 8; ++st) acc[mt][st] = (f32x4){0.f, 0.f, 0.f, 0.f};

#pragma unroll
  for (int kk = 0; kk < 2; ++kk) {
    const int ko = kk * 32 + quad * 8;
    bf16x8 aw[2];
#pragma unroll
    for (int mt = 0; mt < 2; ++mt)
      aw[mt] = ldfrag(&w1s[32 * wv + 16 * mt + lm][ko]);
#pragma unroll
    for (int mt = 0; mt < 2; ++mt)
#pragma unroll
      for (int st = 0; st < 8; ++st)
        acc[mt][st] = __builtin_amdgcn_mfma_f32_16x16x32_bf16(
            aw[mt], bh[kk][st], acc[mt][st], 0, 0, 0);
  }

  // t = relu(acc + b) -> bf16 -> tA[s][j]; lane holds 4 consecutive j
  // at fixed s -> one 8B write per (mt,st).
#pragma unroll
  for (int mt = 0; mt < 2; ++mt) {
    const int jb = 32 * wv + 16 * mt + quad * 4;
    const float4 bj = *(const float4*)&fb1[jb];
#pragma unroll
    for (int st = 0; st < 8; ++st) {
      const int sR = 16 * st + lm;
      const float v0 = fmaxf(acc[mt][st][0] + bj.x, 0.f);
      const float v1 = fmaxf(acc[mt][st][1] + bj.y, 0.f);
      const float v2 = fmaxf(acc[mt][st][2] + bj.z, 0.f);
      const float v3 = fmaxf(acc[mt][st][3] + bj.w, 0.f);
      uint2 pv;
      pv.x = (uint)f2b(v0) | ((uint)f2b(v1) << 16);
      pv.y = (uint)f2b(v2) | ((uint)f2b(v3) << 16);
      *(uint2*)&tA[sR][jb] = pv;
    }
  }
  __syncthreads();   // barrier #2: tA ready

  // ---- phase2 MFMA (swapped): A-frags direct from out_w fp32
  f32x4 acc2[2][8];
#pragma unroll
  for (int mt = 0; mt < 2; ++mt)
#pragma unroll
    for (int st = 0; st < 8; ++st) acc2[mt][st] = (f32x4){0.f, 0.f, 0.f, 0.f};

#pragma unroll
  for (int kk = 0; kk < 4; ++kk) {
    const int ko = kk * 32 + quad * 8;
    bf16x8 ao[2], bt[8];
#pragma unroll
    for (int mt = 0; mt < 2; ++mt) {
      const float* rp = outw + (size_t)(32 * wv + 16 * mt + lm) * 128 + ko;
      const float4 v0 = *(const float4*)rp;
      const float4 v1 = *(const float4*)(rp + 4);
      ao[mt] = pack8(v0, v1);
    }
#pragma unroll
    for (int st = 0; st < 8; ++st)
      bt[st] = ldfrag(&tA[16 * st + lm][ko]);
#pragma unroll
    for (int mt = 0; mt < 2; ++mt)
#pragma unroll
      for (int st = 0; st < 8; ++st)
        acc2[mt][st] = __builtin_amdgcn_mfma_f32_16x16x32_bf16(
            ao[mt], bt[st], acc2[mt][st], 0, 0, 0);
  }

  // epilogue: lane holds 4 consecutive o at fixed s -> dwordx4 stores
#pragma unroll
  for (int mt = 0; mt < 2; ++mt) {
    const int obase = 32 * wv + 16 * mt + quad * 4;
    const float4 b4 = *(const float4*)&ob[obase];
#pragma unroll
    for (int st = 0; st < 8; ++st) {
      const int srow = s0 + 16 * st + lm;
      float4 o4;
      o4.x = acc2[mt][st][0] + b4.x;
      o4.y = acc2[mt][st][1] + b4.y;
      o4.z = acc2[mt][st][2] + b4.z;
      o4.w = acc2[mt][st][3] + b4.w;
      *(float4*)&out[(size_t)srow * 128 + obase] = o4;
    }
  }
}

extern "C" void kernel_launch(void* const* d_in, const int* in_sizes, int n_in,
                              void* d_out, int out_size, void* d_ws, size_t ws_size,
                              hipStream_t stream) {
  const float* x    = (const float*)d_in[0];
  const float* w1   = (const float*)d_in[1];
  const float* b1   = (const float*)d_in[2];
  const float* w2   = (const float*)d_in[3];
  const float* b2   = (const float*)d_in[4];
  const float* fc1w = (const float*)d_in[5];
  const float* fc1b = (const float*)d_in[6];
  const float* outw = (const float*)d_in[7];
  const float* outb = (const float*)d_in[8];
  float* outp = (float*)d_out;
  ushort* ws  = (ushort*)d_ws;   // h2 staging: N x 64 bf16 = 16.8 MB

  const int N = in_sizes[0] / 128;   // 131072

  conv_kernel_r9<<<N / 128, 384, 0, stream>>>(x, w1, b1, w2, b2, ws);
  fc_kernel_r9<<<N / 128, 256, 0, stream>>>(ws, fc1w, fc1b, outw, outb, outp);
}